// Round 1
// baseline (410.751 us; speedup 1.0000x reference)
//
#include <hip/hip_runtime.h>

#define HW 3136
#define W_ 56
#define C_IN 64
#define C_MID 16
#define KK 49
#define NT 64
#define NPIX (NT*HW)          // 200704
#define NF 200704.0f

// ---------------- K1: 1x1 conv 64->16, write raw y, accumulate BN1 sums ----------------
__global__ __launch_bounds__(256) void k1_conv(const float* __restrict__ x,
                                               const float* __restrict__ w21,
                                               float* __restrict__ y,
                                               float* __restrict__ st /* s1[16] then q1[16] */) {
  float s[C_MID], q[C_MID];
#pragma unroll
  for (int o = 0; o < C_MID; ++o) { s[o] = 0.f; q[o] = 0.f; }

  for (int pix = blockIdx.x * 256 + threadIdx.x; pix < NPIX; pix += gridDim.x * 256) {
    int n = pix / HW; int hw = pix - n * HW;
    const float* xp = x + (size_t)n * C_IN * HW + hw;
    float acc[C_MID];
#pragma unroll
    for (int o = 0; o < C_MID; ++o) acc[o] = 0.f;
#pragma unroll
    for (int cb = 0; cb < C_IN; cb += 16) {
      float xv[16];
#pragma unroll
      for (int j = 0; j < 16; ++j) xv[j] = xp[(cb + j) * HW];
#pragma unroll
      for (int o = 0; o < C_MID; ++o) {
        float a = acc[o];
#pragma unroll
        for (int j = 0; j < 16; ++j) a = fmaf(w21[o * C_IN + cb + j], xv[j], a);
        acc[o] = a;
      }
    }
    float* yp = y + (size_t)n * C_MID * HW + hw;
#pragma unroll
    for (int o = 0; o < C_MID; ++o) {
      yp[o * HW] = acc[o];
      s[o] += acc[o];
      q[o] += acc[o] * acc[o];
    }
  }

  // block reduction: 32 slots (16 sums + 16 sumsq), padded to kill bank conflicts
  __shared__ float red[32][257];
#pragma unroll
  for (int o = 0; o < C_MID; ++o) {
    red[o][threadIdx.x] = s[o];
    red[o + 16][threadIdx.x] = q[o];
  }
  __syncthreads();
  if (threadIdx.x < 32) {
    float t = 0.f;
    for (int i = 0; i < 256; ++i) t += red[threadIdx.x][i];
    atomicAdd(&st[threadIdx.x], t);
  }
}

// ---------------- finalize BN params: scale = g/sqrt(var+eps), shift = b - mean*scale ----
__global__ void k_fin(const float* __restrict__ s, const float* __restrict__ q,
                      const float* __restrict__ g, const float* __restrict__ b,
                      float* __restrict__ sc, float* __restrict__ sh, int C) {
  int i = threadIdx.x;
  if (i < C) {
    float m = s[i] * (1.0f / NF);
    float v = q[i] * (1.0f / NF) - m * m;
    float inv = g[i] / sqrtf(v + 1e-5f);
    sc[i] = inv;
    sh[i] = fmaf(-m, inv, b[i]);
  }
}

// ---------------- K3: 7x7x16 shifted correlation ----------------
#define HR 14
#define HC 62
#define HSZ (HR*HC)           // 868
__global__ __launch_bounds__(448) void k3_corr(const float* __restrict__ y,
                                               const float* __restrict__ sc1,
                                               const float* __restrict__ sh1,
                                               float* __restrict__ corr) {
  __shared__ float Bl[C_MID * HSZ];   // 55,552 B
  int tid = threadIdx.x;
  int n = blockIdx.x / 7;
  int rt = blockIdx.x - n * 7;
  int r0 = rt * 8;
  int t = n & 7;
  int n2 = (n & ~7) | (t < 7 ? t + 1 : 7);   // time-shifted frame

  // stage shifted-frame halo (BN1 affine + relu applied here)
  const float* yb = y + (size_t)n2 * C_MID * HW;
  for (int idx = tid; idx < C_MID * HSZ; idx += 448) {
    int c = idx / HSZ; int rem = idx - c * HSZ;
    int rr = rem / HC; int cc = rem - rr * HC;
    int gr = r0 + rr - 3; int gc = cc - 3;
    float v = 0.f;
    if (gr >= 0 && gr < 56 && gc >= 0 && gc < 56) {
      v = yb[c * HW + gr * W_ + gc];
      v = fmaxf(fmaf(sc1[c], v, sh1[c]), 0.f);
    }
    Bl[idx] = v;
  }

  // A pixel (current frame) into registers
  int ty = tid / W_; int tx = tid - ty * W_;
  int r = r0 + ty;
  float a[C_MID];
  const float* ya = y + (size_t)n * C_MID * HW + r * W_ + tx;
#pragma unroll
  for (int c = 0; c < C_MID; ++c)
    a[c] = fmaxf(fmaf(sc1[c], ya[c * HW], sh1[c]), 0.f);

  __syncthreads();

  float* cp = corr + (size_t)n * KK * HW + r * W_ + tx;
#pragma unroll
  for (int dy = 0; dy < 7; ++dy) {
#pragma unroll
    for (int dx = 0; dx < 7; ++dx) {
      const float* bp = Bl + (ty + dy) * HC + (tx + dx);
      float v0 = 0.f, v1 = 0.f;
#pragma unroll
      for (int c = 0; c < C_MID; c += 2) {
        v0 = fmaf(a[c],     bp[c * HSZ],       v0);
        v1 = fmaf(a[c + 1], bp[(c + 1) * HSZ], v1);
      }
      cp[(dy * 7 + dx) * HW] = (v0 + v1) * (1.0f / 16.0f);
    }
  }
}

// ---------------- K3b: per-(n,k) slice stats of corr ----------------
__global__ __launch_bounds__(256) void k3b_stats(const float* __restrict__ corr,
                                                 float* __restrict__ st /* s2[49] then q2[49] */) {
  const float* base = corr + (size_t)blockIdx.x * HW;
  int k = blockIdx.x % KK;
  float s = 0.f, q = 0.f;
  const float4* b4 = (const float4*)base;
  for (int i = threadIdx.x; i < HW / 4; i += 256) {
    float4 v = b4[i];
    s += v.x + v.y + v.z + v.w;
    q += v.x * v.x + v.y * v.y + v.z * v.z + v.w * v.w;
  }
#pragma unroll
  for (int off = 32; off > 0; off >>= 1) {
    s += __shfl_xor(s, off, 64);
    q += __shfl_xor(q, off, 64);
  }
  __shared__ float rs[4], rq[4];
  int wv = threadIdx.x >> 6; int lane = threadIdx.x & 63;
  if (lane == 0) { rs[wv] = s; rq[wv] = q; }
  __syncthreads();
  if (threadIdx.x == 0) {
    atomicAdd(&st[k],      rs[0] + rs[1] + rs[2] + rs[3]);
    atomicAdd(&st[KK + k], rq[0] + rq[1] + rq[2] + rq[3]);
  }
}

// ---------------- K5: 49->64 matvec, BN3 statistics only ----------------
__global__ __launch_bounds__(256) void k5_stats(const float* __restrict__ corr,
                                                const float* __restrict__ sc2,
                                                const float* __restrict__ sh2,
                                                const float* __restrict__ w22,
                                                float* __restrict__ s3, float* __restrict__ q3) {
  __shared__ float aS[64], aQ[64];
  if (threadIdx.x < 64) { aS[threadIdx.x] = 0.f; aQ[threadIdx.x] = 0.f; }
  __syncthreads();
  int lane = threadIdx.x & 63;

  // grid/stride are multiples of 64 and NPIX%64==0 -> whole-wave uniform trip counts (shuffles safe)
  for (int pix = blockIdx.x * 256 + threadIdx.x; pix < NPIX; pix += gridDim.x * 256) {
    int n = pix / HW; int hw = pix - n * HW;
    const float* cp = corr + (size_t)n * KK * HW + hw;
    float cr[KK];
#pragma unroll
    for (int k = 0; k < KK; ++k)
      cr[k] = fmaxf(fmaf(sc2[k], cp[k * HW], sh2[k]), 0.f);

    for (int o = 0; o < 64; ++o) {
      const float* wr = w22 + o * KK;
      float t0 = 0.f, t1 = 0.f, t2 = 0.f, t3 = 0.f;
#pragma unroll
      for (int k = 0; k < 48; k += 4) {
        t0 = fmaf(wr[k],     cr[k],     t0);
        t1 = fmaf(wr[k + 1], cr[k + 1], t1);
        t2 = fmaf(wr[k + 2], cr[k + 2], t2);
        t3 = fmaf(wr[k + 3], cr[k + 3], t3);
      }
      t0 = fmaf(wr[48], cr[48], t0);
      float tt = (t0 + t1) + (t2 + t3);
      float vs = tt, vq = tt * tt;
#pragma unroll
      for (int off = 32; off > 0; off >>= 1) {
        vs += __shfl_xor(vs, off, 64);
        vq += __shfl_xor(vq, off, 64);
      }
      if (lane == 0) { atomicAdd(&aS[o], vs); atomicAdd(&aQ[o], vq); }
    }
  }
  __syncthreads();
  if (threadIdx.x < 64) {
    atomicAdd(&s3[threadIdx.x], aS[threadIdx.x]);
    atomicAdd(&q3[threadIdx.x], aQ[threadIdx.x]);
  }
}

// ---------------- K7: recompute matvec, BN3 + residual + relu, write out ----------------
__global__ __launch_bounds__(256) void k7_out(const float* __restrict__ corr,
                                              const float* __restrict__ sc2,
                                              const float* __restrict__ sh2,
                                              const float* __restrict__ w22,
                                              const float* __restrict__ sc3,
                                              const float* __restrict__ sh3,
                                              const float* __restrict__ x,
                                              float* __restrict__ out) {
  for (int pix = blockIdx.x * 256 + threadIdx.x; pix < NPIX; pix += gridDim.x * 256) {
    int n = pix / HW; int hw = pix - n * HW;
    const float* cp = corr + (size_t)n * KK * HW + hw;
    float cr[KK];
#pragma unroll
    for (int k = 0; k < KK; ++k)
      cr[k] = fmaxf(fmaf(sc2[k], cp[k * HW], sh2[k]), 0.f);

    const float* xp = x + (size_t)n * C_IN * HW + hw;
    float* op = out + (size_t)n * C_IN * HW + hw;
#pragma unroll 4
    for (int o = 0; o < 64; ++o) {
      const float* wr = w22 + o * KK;
      float t0 = 0.f, t1 = 0.f, t2 = 0.f, t3 = 0.f;
#pragma unroll
      for (int k = 0; k < 48; k += 4) {
        t0 = fmaf(wr[k],     cr[k],     t0);
        t1 = fmaf(wr[k + 1], cr[k + 1], t1);
        t2 = fmaf(wr[k + 2], cr[k + 2], t2);
        t3 = fmaf(wr[k + 3], cr[k + 3], t3);
      }
      t0 = fmaf(wr[48], cr[48], t0);
      float tt = (t0 + t1) + (t2 + t3);
      float r = fmaf(sc3[o], tt, sh3[o]) + xp[o * HW];
      op[o * HW] = fmaxf(r, 0.f);
    }
  }
}

extern "C" void kernel_launch(void* const* d_in, const int* in_sizes, int n_in,
                              void* d_out, int out_size, void* d_ws, size_t ws_size,
                              hipStream_t stream) {
  const float* x   = (const float*)d_in[0];
  const float* w21 = (const float*)d_in[1];
  const float* w22 = (const float*)d_in[2];
  const float* g21 = (const float*)d_in[3];
  const float* b21 = (const float*)d_in[4];
  const float* g22 = (const float*)d_in[5];
  const float* b22 = (const float*)d_in[6];
  const float* g23 = (const float*)d_in[7];
  const float* b23 = (const float*)d_in[8];
  float* out = (float*)d_out;

  float* ws   = (float*)d_ws;
  float* y    = ws;                                  // 64*16*3136 = 3,211,264 f
  float* corr = y + (size_t)NT * C_MID * HW;         // 64*49*3136 = 9,834,496 f
  float* st   = corr + (size_t)NT * KK * HW;         // raw sums: 258 f
  float* s1 = st;        float* q1 = s1 + 16;
  float* s2 = q1 + 16;   float* q2 = s2 + KK;
  float* s3 = q2 + KK;   float* q3 = s3 + 64;
  float* sc1 = q3 + 64;  float* sh1 = sc1 + 16;
  float* sc2 = sh1 + 16; float* sh2 = sc2 + KK;
  float* sc3 = sh2 + KK; float* sh3 = sc3 + 64;

  // zero the raw stat accumulators (ws is re-poisoned before every launch)
  hipMemsetAsync(st, 0, 258 * sizeof(float), stream);

  k1_conv  <<<512, 256, 0, stream>>>(x, w21, y, s1);
  k_fin    <<<1,   64,  0, stream>>>(s1, q1, g21, b21, sc1, sh1, C_MID);
  k3_corr  <<<448, 448, 0, stream>>>(y, sc1, sh1, corr);
  k3b_stats<<<NT * KK, 256, 0, stream>>>(corr, s2);
  k_fin    <<<1,   64,  0, stream>>>(s2, q2, g22, b22, sc2, sh2, KK);
  k5_stats <<<512, 256, 0, stream>>>(corr, sc2, sh2, w22, s3, q3);
  k_fin    <<<1,   64,  0, stream>>>(s3, q3, g23, b23, sc3, sh3, C_IN);
  k7_out   <<<1024, 256, 0, stream>>>(corr, sc2, sh2, w22, sc3, sh3, x, out);
}

// Round 2
// 305.585 us; speedup vs baseline: 1.3441x; 1.3441x over previous
//
#include <hip/hip_runtime.h>

#define HW 3136
#define W_ 56
#define C_IN 64
#define C_MID 16
#define KK 49
#define NT 64
#define NPIX (NT*HW)          // 200704
#define NF 200704.0f

// ---------------- K1: 1x1 conv 64->16, write raw y, accumulate BN1 sums ----------------
__global__ __launch_bounds__(256) void k1_conv(const float* __restrict__ x,
                                               const float* __restrict__ w21,
                                               float* __restrict__ y,
                                               float* __restrict__ st /* s1[16] then q1[16] */) {
  float s[C_MID], q[C_MID];
#pragma unroll
  for (int o = 0; o < C_MID; ++o) { s[o] = 0.f; q[o] = 0.f; }

  for (int pix = blockIdx.x * 256 + threadIdx.x; pix < NPIX; pix += gridDim.x * 256) {
    int n = pix / HW; int hw = pix - n * HW;
    const float* xp = x + (size_t)n * C_IN * HW + hw;
    float acc[C_MID];
#pragma unroll
    for (int o = 0; o < C_MID; ++o) acc[o] = 0.f;
#pragma unroll
    for (int cb = 0; cb < C_IN; cb += 16) {
      float xv[16];
#pragma unroll
      for (int j = 0; j < 16; ++j) xv[j] = xp[(cb + j) * HW];
#pragma unroll
      for (int o = 0; o < C_MID; ++o) {
        float a = acc[o];
#pragma unroll
        for (int j = 0; j < 16; ++j) a = fmaf(w21[o * C_IN + cb + j], xv[j], a);
        acc[o] = a;
      }
    }
    float* yp = y + (size_t)n * C_MID * HW + hw;
#pragma unroll
    for (int o = 0; o < C_MID; ++o) {
      yp[o * HW] = acc[o];
      s[o] += acc[o];
      q[o] += acc[o] * acc[o];
    }
  }

  // wave shuffle reduce (all 32 values), then cross-wave LDS combine, 32 atomics/block
  __shared__ float combS[C_MID][4], combQ[C_MID][4];
  int wv = threadIdx.x >> 6;
  int lane = threadIdx.x & 63;
#pragma unroll
  for (int o = 0; o < C_MID; ++o) {
    float a = s[o], b = q[o];
#pragma unroll
    for (int off = 32; off > 0; off >>= 1) {
      a += __shfl_xor(a, off, 64);
      b += __shfl_xor(b, off, 64);
    }
    if (lane == 0) { combS[o][wv] = a; combQ[o][wv] = b; }
  }
  __syncthreads();
  if (threadIdx.x < 32) {
    int o = threadIdx.x & 15;
    float t = (threadIdx.x < 16)
      ? (combS[o][0] + combS[o][1] + combS[o][2] + combS[o][3])
      : (combQ[o][0] + combQ[o][1] + combQ[o][2] + combQ[o][3]);
    atomicAdd(&st[threadIdx.x], t);
  }
}

// ---------------- finalize BN params: scale = g/sqrt(var+eps), shift = b - mean*scale ----
__global__ void k_fin(const float* __restrict__ s, const float* __restrict__ q,
                      const float* __restrict__ g, const float* __restrict__ b,
                      float* __restrict__ sc, float* __restrict__ sh, int C) {
  int i = threadIdx.x;
  if (i < C) {
    float m = s[i] * (1.0f / NF);
    float v = q[i] * (1.0f / NF) - m * m;
    float inv = g[i] / sqrtf(v + 1e-5f);
    sc[i] = inv;
    sh[i] = fmaf(-m, inv, b[i]);
  }
}

// ---------------- K3: 7x7x16 shifted correlation ----------------
#define HR 14
#define HC 62
#define HSZ (HR*HC)           // 868
__global__ __launch_bounds__(448) void k3_corr(const float* __restrict__ y,
                                               const float* __restrict__ sc1,
                                               const float* __restrict__ sh1,
                                               float* __restrict__ corr) {
  __shared__ float Bl[C_MID * HSZ];   // 55,552 B
  int tid = threadIdx.x;
  int n = blockIdx.x / 7;
  int rt = blockIdx.x - n * 7;
  int r0 = rt * 8;
  int t = n & 7;
  int n2 = (n & ~7) | (t < 7 ? t + 1 : 7);   // time-shifted frame

  // stage shifted-frame halo (BN1 affine + relu applied here)
  const float* yb = y + (size_t)n2 * C_MID * HW;
  for (int idx = tid; idx < C_MID * HSZ; idx += 448) {
    int c = idx / HSZ; int rem = idx - c * HSZ;
    int rr = rem / HC; int cc = rem - rr * HC;
    int gr = r0 + rr - 3; int gc = cc - 3;
    float v = 0.f;
    if (gr >= 0 && gr < 56 && gc >= 0 && gc < 56) {
      v = yb[c * HW + gr * W_ + gc];
      v = fmaxf(fmaf(sc1[c], v, sh1[c]), 0.f);
    }
    Bl[idx] = v;
  }

  // A pixel (current frame) into registers
  int ty = tid / W_; int tx = tid - ty * W_;
  int r = r0 + ty;
  float a[C_MID];
  const float* ya = y + (size_t)n * C_MID * HW + r * W_ + tx;
#pragma unroll
  for (int c = 0; c < C_MID; ++c)
    a[c] = fmaxf(fmaf(sc1[c], ya[c * HW], sh1[c]), 0.f);

  __syncthreads();

  float* cp = corr + (size_t)n * KK * HW + r * W_ + tx;
#pragma unroll
  for (int dy = 0; dy < 7; ++dy) {
#pragma unroll
    for (int dx = 0; dx < 7; ++dx) {
      const float* bp = Bl + (ty + dy) * HC + (tx + dx);
      float v0 = 0.f, v1 = 0.f;
#pragma unroll
      for (int c = 0; c < C_MID; c += 2) {
        v0 = fmaf(a[c],     bp[c * HSZ],       v0);
        v1 = fmaf(a[c + 1], bp[(c + 1) * HSZ], v1);
      }
      cp[(dy * 7 + dx) * HW] = (v0 + v1) * (1.0f / 16.0f);
    }
  }
}

// ---------------- K3b: per-(n,k) slice stats of corr ----------------
__global__ __launch_bounds__(256) void k3b_stats(const float* __restrict__ corr,
                                                 float* __restrict__ st /* s2[49] then q2[49] */) {
  const float* base = corr + (size_t)blockIdx.x * HW;
  int k = blockIdx.x % KK;
  float s = 0.f, q = 0.f;
  const float4* b4 = (const float4*)base;
  for (int i = threadIdx.x; i < HW / 4; i += 256) {
    float4 v = b4[i];
    s += v.x + v.y + v.z + v.w;
    q += v.x * v.x + v.y * v.y + v.z * v.z + v.w * v.w;
  }
#pragma unroll
  for (int off = 32; off > 0; off >>= 1) {
    s += __shfl_xor(s, off, 64);
    q += __shfl_xor(q, off, 64);
  }
  __shared__ float rs[4], rq[4];
  int wv = threadIdx.x >> 6; int lane = threadIdx.x & 63;
  if (lane == 0) { rs[wv] = s; rq[wv] = q; }
  __syncthreads();
  if (threadIdx.x == 0) {
    atomicAdd(&st[k],      rs[0] + rs[1] + rs[2] + rs[3]);
    atomicAdd(&st[KK + k], rq[0] + rq[1] + rq[2] + rq[3]);
  }
}

// ---------------- K5_mat: 49->64 matvec, store pre-BN3 tt (no stats) ----------------
__global__ __launch_bounds__(256) void k5_mat(const float* __restrict__ corr,
                                              const float* __restrict__ sc2,
                                              const float* __restrict__ sh2,
                                              const float* __restrict__ w22,
                                              float* __restrict__ tt) {
  int pix = blockIdx.x * 256 + threadIdx.x;   // grid = 784 exactly covers NPIX
  int n = pix / HW; int hw = pix - n * HW;
  const float* cp = corr + (size_t)n * KK * HW + hw;
  float cr[KK];
#pragma unroll
  for (int k = 0; k < KK; ++k)
    cr[k] = fmaxf(fmaf(sc2[k], cp[k * HW], sh2[k]), 0.f);

  float* tp = tt + (size_t)n * C_IN * HW + hw;
#pragma unroll 4
  for (int o = 0; o < 64; ++o) {
    const float* wr = w22 + o * KK;
    float t0 = 0.f, t1 = 0.f, t2 = 0.f, t3 = 0.f;
#pragma unroll
    for (int k = 0; k < 48; k += 4) {
      t0 = fmaf(wr[k],     cr[k],     t0);
      t1 = fmaf(wr[k + 1], cr[k + 1], t1);
      t2 = fmaf(wr[k + 2], cr[k + 2], t2);
      t3 = fmaf(wr[k + 3], cr[k + 3], t3);
    }
    t0 = fmaf(wr[48], cr[48], t0);
    tp[o * HW] = (t0 + t1) + (t2 + t3);
  }
}

// ---------------- K5b: per-(n,o) plane stats of tt (pure BW) ----------------
__global__ __launch_bounds__(256) void k5b_stats(const float* __restrict__ tt,
                                                 float* __restrict__ st /* s3[64] then q3[64] */) {
  const float4* b4 = (const float4*)(tt + (size_t)blockIdx.x * HW);
  int o = blockIdx.x & 63;
  float s = 0.f, q = 0.f;
  for (int i = threadIdx.x; i < HW / 4; i += 256) {
    float4 v = b4[i];
    s += v.x + v.y + v.z + v.w;
    q += v.x * v.x + v.y * v.y + v.z * v.z + v.w * v.w;
  }
#pragma unroll
  for (int off = 32; off > 0; off >>= 1) {
    s += __shfl_xor(s, off, 64);
    q += __shfl_xor(q, off, 64);
  }
  __shared__ float rs[4], rq[4];
  int wv = threadIdx.x >> 6; int lane = threadIdx.x & 63;
  if (lane == 0) { rs[wv] = s; rq[wv] = q; }
  __syncthreads();
  if (threadIdx.x == 0) {
    atomicAdd(&st[o],      rs[0] + rs[1] + rs[2] + rs[3]);
    atomicAdd(&st[64 + o], rq[0] + rq[1] + rq[2] + rq[3]);
  }
}

// ---------------- K7_ew: elementwise BN3 + residual + relu ----------------
__global__ __launch_bounds__(256) void k7_ew(const float* __restrict__ tt,
                                             const float* __restrict__ sc3,
                                             const float* __restrict__ sh3,
                                             const float* __restrict__ x,
                                             float* __restrict__ out) {
  const int tot4 = NPIX * C_IN / 4;   // 3,211,264
  const float4* t4 = (const float4*)tt;
  const float4* x4 = (const float4*)x;
  float4* o4 = (float4*)out;
  for (int i = blockIdx.x * 256 + threadIdx.x; i < tot4; i += gridDim.x * 256) {
    int plane = i / (HW / 4);
    int o = plane & 63;
    float a = sc3[o], b = sh3[o];
    float4 t = t4[i];
    float4 xv = x4[i];
    float4 r;
    r.x = fmaxf(fmaf(a, t.x, b) + xv.x, 0.f);
    r.y = fmaxf(fmaf(a, t.y, b) + xv.y, 0.f);
    r.z = fmaxf(fmaf(a, t.z, b) + xv.z, 0.f);
    r.w = fmaxf(fmaf(a, t.w, b) + xv.w, 0.f);
    o4[i] = r;
  }
}

// ---------------- Fallback K5: 49->64 matvec, BN3 statistics only (round-1) ----------------
__global__ __launch_bounds__(256) void k5_stats(const float* __restrict__ corr,
                                                const float* __restrict__ sc2,
                                                const float* __restrict__ sh2,
                                                const float* __restrict__ w22,
                                                float* __restrict__ s3, float* __restrict__ q3) {
  __shared__ float aS[64], aQ[64];
  if (threadIdx.x < 64) { aS[threadIdx.x] = 0.f; aQ[threadIdx.x] = 0.f; }
  __syncthreads();
  int lane = threadIdx.x & 63;
  for (int pix = blockIdx.x * 256 + threadIdx.x; pix < NPIX; pix += gridDim.x * 256) {
    int n = pix / HW; int hw = pix - n * HW;
    const float* cp = corr + (size_t)n * KK * HW + hw;
    float cr[KK];
#pragma unroll
    for (int k = 0; k < KK; ++k)
      cr[k] = fmaxf(fmaf(sc2[k], cp[k * HW], sh2[k]), 0.f);
    for (int o = 0; o < 64; ++o) {
      const float* wr = w22 + o * KK;
      float t0 = 0.f, t1 = 0.f, t2 = 0.f, t3 = 0.f;
#pragma unroll
      for (int k = 0; k < 48; k += 4) {
        t0 = fmaf(wr[k],     cr[k],     t0);
        t1 = fmaf(wr[k + 1], cr[k + 1], t1);
        t2 = fmaf(wr[k + 2], cr[k + 2], t2);
        t3 = fmaf(wr[k + 3], cr[k + 3], t3);
      }
      t0 = fmaf(wr[48], cr[48], t0);
      float ttv = (t0 + t1) + (t2 + t3);
      float vs = ttv, vq = ttv * ttv;
#pragma unroll
      for (int off = 32; off > 0; off >>= 1) {
        vs += __shfl_xor(vs, off, 64);
        vq += __shfl_xor(vq, off, 64);
      }
      if (lane == 0) { atomicAdd(&aS[o], vs); atomicAdd(&aQ[o], vq); }
    }
  }
  __syncthreads();
  if (threadIdx.x < 64) {
    atomicAdd(&s3[threadIdx.x], aS[threadIdx.x]);
    atomicAdd(&q3[threadIdx.x], aQ[threadIdx.x]);
  }
}

// ---------------- Fallback K7: recompute matvec, BN3 + residual + relu ----------------
__global__ __launch_bounds__(256) void k7_out(const float* __restrict__ corr,
                                              const float* __restrict__ sc2,
                                              const float* __restrict__ sh2,
                                              const float* __restrict__ w22,
                                              const float* __restrict__ sc3,
                                              const float* __restrict__ sh3,
                                              const float* __restrict__ x,
                                              float* __restrict__ out) {
  for (int pix = blockIdx.x * 256 + threadIdx.x; pix < NPIX; pix += gridDim.x * 256) {
    int n = pix / HW; int hw = pix - n * HW;
    const float* cp = corr + (size_t)n * KK * HW + hw;
    float cr[KK];
#pragma unroll
    for (int k = 0; k < KK; ++k)
      cr[k] = fmaxf(fmaf(sc2[k], cp[k * HW], sh2[k]), 0.f);
    const float* xp = x + (size_t)n * C_IN * HW + hw;
    float* op = out + (size_t)n * C_IN * HW + hw;
#pragma unroll 4
    for (int o = 0; o < 64; ++o) {
      const float* wr = w22 + o * KK;
      float t0 = 0.f, t1 = 0.f, t2 = 0.f, t3 = 0.f;
#pragma unroll
      for (int k = 0; k < 48; k += 4) {
        t0 = fmaf(wr[k],     cr[k],     t0);
        t1 = fmaf(wr[k + 1], cr[k + 1], t1);
        t2 = fmaf(wr[k + 2], cr[k + 2], t2);
        t3 = fmaf(wr[k + 3], cr[k + 3], t3);
      }
      t0 = fmaf(wr[48], cr[48], t0);
      float ttv = (t0 + t1) + (t2 + t3);
      float r = fmaf(sc3[o], ttv, sh3[o]) + xp[o * HW];
      op[o * HW] = fmaxf(r, 0.f);
    }
  }
}

extern "C" void kernel_launch(void* const* d_in, const int* in_sizes, int n_in,
                              void* d_out, int out_size, void* d_ws, size_t ws_size,
                              hipStream_t stream) {
  const float* x   = (const float*)d_in[0];
  const float* w21 = (const float*)d_in[1];
  const float* w22 = (const float*)d_in[2];
  const float* g21 = (const float*)d_in[3];
  const float* b21 = (const float*)d_in[4];
  const float* g22 = (const float*)d_in[5];
  const float* b22 = (const float*)d_in[6];
  const float* g23 = (const float*)d_in[7];
  const float* b23 = (const float*)d_in[8];
  float* out = (float*)d_out;

  const size_t Y_F    = (size_t)NT * C_MID * HW;   // 3,211,264
  const size_t CORR_F = (size_t)NT * KK * HW;      // 9,834,496
  const size_t TT_F   = (size_t)NT * C_IN * HW;    // 12,845,056
  const size_t ST_F   = 1024;

  float* ws   = (float*)d_ws;
  float* y    = ws;
  float* corr = y + Y_F;
  float* st   = corr + CORR_F;
  float* tt   = st + ST_F;

  float* s1 = st;        float* q1 = s1 + 16;      // raw sums: st[0..257]
  float* s2 = q1 + 16;   float* q2 = s2 + KK;
  float* s3 = q2 + KK;   float* q3 = s3 + 64;
  float* sc1 = st + 300; float* sh1 = sc1 + 16;
  float* sc2 = sh1 + 16; float* sh2 = sc2 + KK;
  float* sc3 = sh2 + KK; float* sh3 = sc3 + 64;

  bool fast = ws_size >= (Y_F + CORR_F + ST_F + TT_F) * sizeof(float);

  hipMemsetAsync(st, 0, 258 * sizeof(float), stream);

  k1_conv  <<<512, 256, 0, stream>>>(x, w21, y, s1);
  k_fin    <<<1,   64,  0, stream>>>(s1, q1, g21, b21, sc1, sh1, C_MID);
  k3_corr  <<<448, 448, 0, stream>>>(y, sc1, sh1, corr);
  k3b_stats<<<NT * KK, 256, 0, stream>>>(corr, s2);
  k_fin    <<<1,   64,  0, stream>>>(s2, q2, g22, b22, sc2, sh2, KK);

  if (fast) {
    k5_mat  <<<NPIX / 256, 256, 0, stream>>>(corr, sc2, sh2, w22, tt);
    k5b_stats<<<NT * C_IN, 256, 0, stream>>>(tt, s3);
    k_fin   <<<1,   64,  0, stream>>>(s3, q3, g23, b23, sc3, sh3, C_IN);
    k7_ew   <<<2048, 256, 0, stream>>>(tt, sc3, sh3, x, out);
  } else {
    k5_stats<<<512, 256, 0, stream>>>(corr, sc2, sh2, w22, s3, q3);
    k_fin   <<<1,   64,  0, stream>>>(s3, q3, g23, b23, sc3, sh3, C_IN);
    k7_out  <<<1024, 256, 0, stream>>>(corr, sc2, sh2, w22, sc3, sh3, x, out);
  }
}

// Round 3
// 294.076 us; speedup vs baseline: 1.3967x; 1.0391x over previous
//
#include <hip/hip_runtime.h>

#define HW 3136
#define W_ 56
#define C_IN 64
#define C_MID 16
#define KK 49
#define NT 64
#define NPIX (NT*HW)          // 200704
#define NF 200704.0f
#define EPS 1e-5f

// ---------------- K1: 1x1 conv 64->16, write y as channel-paired float2, BN1 sums ------
__global__ __launch_bounds__(256) void k1_conv(const float* __restrict__ x,
                                               const float* __restrict__ w21,
                                               float2* __restrict__ y2,
                                               float* __restrict__ st /* s1[16] q1[16] */) {
  float s[C_MID], q[C_MID];
#pragma unroll
  for (int o = 0; o < C_MID; ++o) { s[o] = 0.f; q[o] = 0.f; }

  for (int pix = blockIdx.x * 256 + threadIdx.x; pix < NPIX; pix += gridDim.x * 256) {
    int n = pix / HW; int hw = pix - n * HW;
    const float* xp = x + (size_t)n * C_IN * HW + hw;
    float acc[C_MID];
#pragma unroll
    for (int o = 0; o < C_MID; ++o) acc[o] = 0.f;
#pragma unroll
    for (int cb = 0; cb < C_IN; cb += 16) {
      float xv[16];
#pragma unroll
      for (int j = 0; j < 16; ++j) xv[j] = xp[(cb + j) * HW];
#pragma unroll
      for (int o = 0; o < C_MID; ++o) {
        float a = acc[o];
#pragma unroll
        for (int j = 0; j < 16; ++j) a = fmaf(w21[o * C_IN + cb + j], xv[j], a);
        acc[o] = a;
      }
    }
    float2* yp = y2 + (size_t)n * 8 * HW + hw;
#pragma unroll
    for (int c2 = 0; c2 < 8; ++c2) {
      yp[c2 * HW] = make_float2(acc[2 * c2], acc[2 * c2 + 1]);
    }
#pragma unroll
    for (int o = 0; o < C_MID; ++o) {
      s[o] += acc[o];
      q[o] += acc[o] * acc[o];
    }
  }

  __shared__ float combS[C_MID][4], combQ[C_MID][4];
  int wv = threadIdx.x >> 6;
  int lane = threadIdx.x & 63;
#pragma unroll
  for (int o = 0; o < C_MID; ++o) {
    float a = s[o], b = q[o];
#pragma unroll
    for (int off = 32; off > 0; off >>= 1) {
      a += __shfl_xor(a, off, 64);
      b += __shfl_xor(b, off, 64);
    }
    if (lane == 0) { combS[o][wv] = a; combQ[o][wv] = b; }
  }
  __syncthreads();
  if (threadIdx.x < 32) {
    int o = threadIdx.x & 15;
    float t = (threadIdx.x < 16)
      ? (combS[o][0] + combS[o][1] + combS[o][2] + combS[o][3])
      : (combQ[o][0] + combQ[o][1] + combQ[o][2] + combQ[o][3]);
    atomicAdd(&st[threadIdx.x], t);
  }
}

// ---------------- k_fin (fallback path only) --------------------------------------------
__global__ void k_fin(const float* __restrict__ s, const float* __restrict__ q,
                      const float* __restrict__ g, const float* __restrict__ b,
                      float* __restrict__ sc, float* __restrict__ sh, int C) {
  int i = threadIdx.x;
  if (i < C) {
    float m = s[i] * (1.0f / NF);
    float v = q[i] * (1.0f / NF) - m * m;
    float inv = g[i] / sqrtf(v + EPS);
    sc[i] = inv;
    sh[i] = fmaf(-m, inv, b[i]);
  }
}

// ---------------- K3: 7x7x16 shifted correlation (float2 channels, fused BN1) -----------
// 512 blocks (= exactly 2/CU), 7-row tiles, 392 threads; halo 13x62, c2-paired LDS.
#define TR 7
#define HR 13
#define HC 62
#define HSZ2 (HR*HC)          // 806 float2 per c2-plane
__global__ __launch_bounds__(392) void k3_corr(const float2* __restrict__ y2,
                                               const float* __restrict__ st /* s1,q1 */,
                                               const float* __restrict__ g21,
                                               const float* __restrict__ b21,
                                               float* __restrict__ corr) {
  __shared__ float2 Bl[8 * HSZ2];   // 51,584 B
  __shared__ float4 bn1[8];         // (scA, shA, scB, shB) per channel pair
  int tid = threadIdx.x;
  int n = blockIdx.x >> 3;
  int rt = blockIdx.x & 7;
  int r0 = rt * TR;
  int t = n & 7;
  int n2 = (n & ~7) | (t < 7 ? t + 1 : 7);   // time-shifted frame

  if (tid < 8) {
    int cA = 2 * tid, cB = 2 * tid + 1;
    float mA = st[cA] * (1.0f / NF), mB = st[cB] * (1.0f / NF);
    float vA = st[16 + cA] * (1.0f / NF) - mA * mA;
    float vB = st[16 + cB] * (1.0f / NF) - mB * mB;
    float iA = g21[cA] / sqrtf(vA + EPS);
    float iB = g21[cB] / sqrtf(vB + EPS);
    bn1[tid] = make_float4(iA, fmaf(-mA, iA, b21[cA]), iB, fmaf(-mB, iB, b21[cB]));
  }
  __syncthreads();

  // stage shifted-frame halo (post-BN1+relu; out-of-bounds = exact 0)
  const float2* yb = y2 + (size_t)n2 * 8 * HW;
  for (int idx = tid; idx < 8 * HSZ2; idx += 392) {
    int c2 = idx / HSZ2; int rem = idx - c2 * HSZ2;
    int rr = rem / HC; int cc = rem - rr * HC;
    int gr = r0 + rr - 3; int gc = cc - 3;
    float2 v = make_float2(0.f, 0.f);
    if (gr >= 0 && gr < 56 && gc >= 0 && gc < 56) {
      float2 raw = yb[c2 * HW + gr * W_ + gc];
      float4 p = bn1[c2];
      v.x = fmaxf(fmaf(p.x, raw.x, p.y), 0.f);
      v.y = fmaxf(fmaf(p.z, raw.y, p.w), 0.f);
    }
    Bl[idx] = v;
  }

  // A pixel (current frame) into registers
  int ty = tid / W_; int tx = tid - ty * W_;   // ty in [0,7)
  int r = r0 + ty;
  float2 a2[8];
  const float2* ya = y2 + (size_t)n * 8 * HW + r * W_ + tx;
#pragma unroll
  for (int c2 = 0; c2 < 8; ++c2) {
    float2 raw = ya[c2 * HW];
    float4 p = bn1[c2];
    a2[c2] = make_float2(fmaxf(fmaf(p.x, raw.x, p.y), 0.f),
                         fmaxf(fmaf(p.z, raw.y, p.w), 0.f));
  }

  __syncthreads();

  float* cp = corr + (size_t)n * KK * HW + r * W_ + tx;
#pragma unroll
  for (int dy = 0; dy < 7; ++dy) {
#pragma unroll
    for (int dx = 0; dx < 7; ++dx) {
      const float2* bp = Bl + (ty + dy) * HC + (tx + dx);
      float v0 = 0.f, v1 = 0.f;
#pragma unroll
      for (int c2 = 0; c2 < 8; ++c2) {
        float2 bv = bp[c2 * HSZ2];
        v0 = fmaf(a2[c2].x, bv.x, v0);
        v1 = fmaf(a2[c2].y, bv.y, v1);
      }
      cp[(dy * 7 + dx) * HW] = (v0 + v1) * (1.0f / 16.0f);
    }
  }
}

// ---------------- K3b: per-(n,k) slice stats of corr ----------------
__global__ __launch_bounds__(256) void k3b_stats(const float* __restrict__ corr,
                                                 float* __restrict__ st /* s2[49] q2[49] */) {
  const float* base = corr + (size_t)blockIdx.x * HW;
  int k = blockIdx.x % KK;
  float s = 0.f, q = 0.f;
  const float4* b4 = (const float4*)base;
  for (int i = threadIdx.x; i < HW / 4; i += 256) {
    float4 v = b4[i];
    s += v.x + v.y + v.z + v.w;
    q += v.x * v.x + v.y * v.y + v.z * v.z + v.w * v.w;
  }
#pragma unroll
  for (int off = 32; off > 0; off >>= 1) {
    s += __shfl_xor(s, off, 64);
    q += __shfl_xor(q, off, 64);
  }
  __shared__ float rs[4], rq[4];
  int wv = threadIdx.x >> 6; int lane = threadIdx.x & 63;
  if (lane == 0) { rs[wv] = s; rq[wv] = q; }
  __syncthreads();
  if (threadIdx.x == 0) {
    atomicAdd(&st[k],      rs[0] + rs[1] + rs[2] + rs[3]);
    atomicAdd(&st[KK + k], rq[0] + rq[1] + rq[2] + rq[3]);
  }
}

// ---------------- K5_mat: 49->64 matvec, fused BN2, store pre-BN3 tt --------------------
// launch_bounds(256,3): grid caps occupancy at ~12 waves/CU anyway; 170-VGPR budget keeps
// cr[49] resident (VGPR=56 in round 2 -> compiler rematerialized cr from memory, ~3136
// VMEM issues/thread = the 51 us).
__global__ __launch_bounds__(256, 3) void k5_mat(const float* __restrict__ corr,
                                                 const float* __restrict__ st /* s2,q2 */,
                                                 const float* __restrict__ g22,
                                                 const float* __restrict__ b22,
                                                 const float* __restrict__ w22,
                                                 float* __restrict__ tt) {
  __shared__ float bsc[KK], bsh[KK];
  if (threadIdx.x < KK) {
    int k = threadIdx.x;
    float m = st[k] * (1.0f / NF);
    float v = st[KK + k] * (1.0f / NF) - m * m;
    float inv = g22[k] / sqrtf(v + EPS);
    bsc[k] = inv;
    bsh[k] = fmaf(-m, inv, b22[k]);
  }
  __syncthreads();

  int pix = blockIdx.x * 256 + threadIdx.x;   // grid = 784 exactly covers NPIX
  int n = pix / HW; int hw = pix - n * HW;
  const float* cp = corr + (size_t)n * KK * HW + hw;
  float cr[KK];
#pragma unroll
  for (int k = 0; k < KK; ++k)
    cr[k] = fmaxf(fmaf(bsc[k], cp[k * HW], bsh[k]), 0.f);

  float* tp = tt + (size_t)n * C_IN * HW + hw;
#pragma unroll 4
  for (int o = 0; o < 64; ++o) {
    const float* wr = w22 + o * KK;
    float t0 = 0.f, t1 = 0.f, t2 = 0.f, t3 = 0.f;
#pragma unroll
    for (int k = 0; k < 48; k += 4) {
      t0 = fmaf(wr[k],     cr[k],     t0);
      t1 = fmaf(wr[k + 1], cr[k + 1], t1);
      t2 = fmaf(wr[k + 2], cr[k + 2], t2);
      t3 = fmaf(wr[k + 3], cr[k + 3], t3);
    }
    t0 = fmaf(wr[48], cr[48], t0);
    tp[o * HW] = (t0 + t1) + (t2 + t3);
  }
}

// ---------------- K5b: per-(n,o) plane stats of tt (pure BW) ----------------
__global__ __launch_bounds__(256) void k5b_stats(const float* __restrict__ tt,
                                                 float* __restrict__ st /* s3[64] q3[64] */) {
  const float4* b4 = (const float4*)(tt + (size_t)blockIdx.x * HW);
  int o = blockIdx.x & 63;
  float s = 0.f, q = 0.f;
  for (int i = threadIdx.x; i < HW / 4; i += 256) {
    float4 v = b4[i];
    s += v.x + v.y + v.z + v.w;
    q += v.x * v.x + v.y * v.y + v.z * v.z + v.w * v.w;
  }
#pragma unroll
  for (int off = 32; off > 0; off >>= 1) {
    s += __shfl_xor(s, off, 64);
    q += __shfl_xor(q, off, 64);
  }
  __shared__ float rs[4], rq[4];
  int wv = threadIdx.x >> 6; int lane = threadIdx.x & 63;
  if (lane == 0) { rs[wv] = s; rq[wv] = q; }
  __syncthreads();
  if (threadIdx.x == 0) {
    atomicAdd(&st[o],      rs[0] + rs[1] + rs[2] + rs[3]);
    atomicAdd(&st[64 + o], rq[0] + rq[1] + rq[2] + rq[3]);
  }
}

// ---------------- K7_ew: fused BN3 + residual + relu ----------------
__global__ __launch_bounds__(256) void k7_ew(const float* __restrict__ tt,
                                             const float* __restrict__ st /* s3,q3 */,
                                             const float* __restrict__ g23,
                                             const float* __restrict__ b23,
                                             const float* __restrict__ x,
                                             float* __restrict__ out) {
  __shared__ float csc[64], csh[64];
  if (threadIdx.x < 64) {
    int o = threadIdx.x;
    float m = st[o] * (1.0f / NF);
    float v = st[64 + o] * (1.0f / NF) - m * m;
    float inv = g23[o] / sqrtf(v + EPS);
    csc[o] = inv;
    csh[o] = fmaf(-m, inv, b23[o]);
  }
  __syncthreads();

  const int tot4 = NPIX * C_IN / 4;   // 3,211,264
  const float4* t4 = (const float4*)tt;
  const float4* x4 = (const float4*)x;
  float4* o4 = (float4*)out;
  for (int i = blockIdx.x * 256 + threadIdx.x; i < tot4; i += gridDim.x * 256) {
    int plane = i / (HW / 4);
    int o = plane & 63;
    float a = csc[o], b = csh[o];
    float4 t = t4[i];
    float4 xv = x4[i];
    float4 r;
    r.x = fmaxf(fmaf(a, t.x, b) + xv.x, 0.f);
    r.y = fmaxf(fmaf(a, t.y, b) + xv.y, 0.f);
    r.z = fmaxf(fmaf(a, t.z, b) + xv.z, 0.f);
    r.w = fmaxf(fmaf(a, t.w, b) + xv.w, 0.f);
    o4[i] = r;
  }
}

// ---------------- Fallback K5: matvec + BN3 stats only (small-ws path) ------------------
__global__ __launch_bounds__(256, 3) void k5_stats(const float* __restrict__ corr,
                                                   const float* __restrict__ sc2,
                                                   const float* __restrict__ sh2,
                                                   const float* __restrict__ w22,
                                                   float* __restrict__ s3, float* __restrict__ q3) {
  __shared__ float aS[64], aQ[64];
  if (threadIdx.x < 64) { aS[threadIdx.x] = 0.f; aQ[threadIdx.x] = 0.f; }
  __syncthreads();
  int lane = threadIdx.x & 63;
  for (int pix = blockIdx.x * 256 + threadIdx.x; pix < NPIX; pix += gridDim.x * 256) {
    int n = pix / HW; int hw = pix - n * HW;
    const float* cp = corr + (size_t)n * KK * HW + hw;
    float cr[KK];
#pragma unroll
    for (int k = 0; k < KK; ++k)
      cr[k] = fmaxf(fmaf(sc2[k], cp[k * HW], sh2[k]), 0.f);
    for (int o = 0; o < 64; ++o) {
      const float* wr = w22 + o * KK;
      float t0 = 0.f, t1 = 0.f, t2 = 0.f, t3 = 0.f;
#pragma unroll
      for (int k = 0; k < 48; k += 4) {
        t0 = fmaf(wr[k],     cr[k],     t0);
        t1 = fmaf(wr[k + 1], cr[k + 1], t1);
        t2 = fmaf(wr[k + 2], cr[k + 2], t2);
        t3 = fmaf(wr[k + 3], cr[k + 3], t3);
      }
      t0 = fmaf(wr[48], cr[48], t0);
      float ttv = (t0 + t1) + (t2 + t3);
      float vs = ttv, vq = ttv * ttv;
#pragma unroll
      for (int off = 32; off > 0; off >>= 1) {
        vs += __shfl_xor(vs, off, 64);
        vq += __shfl_xor(vq, off, 64);
      }
      if (lane == 0) { atomicAdd(&aS[o], vs); atomicAdd(&aQ[o], vq); }
    }
  }
  __syncthreads();
  if (threadIdx.x < 64) {
    atomicAdd(&s3[threadIdx.x], aS[threadIdx.x]);
    atomicAdd(&q3[threadIdx.x], aQ[threadIdx.x]);
  }
}

// ---------------- Fallback K7: recompute matvec + BN3 + residual + relu -----------------
__global__ __launch_bounds__(256, 3) void k7_out(const float* __restrict__ corr,
                                                 const float* __restrict__ sc2,
                                                 const float* __restrict__ sh2,
                                                 const float* __restrict__ w22,
                                                 const float* __restrict__ sc3,
                                                 const float* __restrict__ sh3,
                                                 const float* __restrict__ x,
                                                 float* __restrict__ out) {
  for (int pix = blockIdx.x * 256 + threadIdx.x; pix < NPIX; pix += gridDim.x * 256) {
    int n = pix / HW; int hw = pix - n * HW;
    const float* cp = corr + (size_t)n * KK * HW + hw;
    float cr[KK];
#pragma unroll
    for (int k = 0; k < KK; ++k)
      cr[k] = fmaxf(fmaf(sc2[k], cp[k * HW], sh2[k]), 0.f);
    const float* xp = x + (size_t)n * C_IN * HW + hw;
    float* op = out + (size_t)n * C_IN * HW + hw;
#pragma unroll 4
    for (int o = 0; o < 64; ++o) {
      const float* wr = w22 + o * KK;
      float t0 = 0.f, t1 = 0.f, t2 = 0.f, t3 = 0.f;
#pragma unroll
      for (int k = 0; k < 48; k += 4) {
        t0 = fmaf(wr[k],     cr[k],     t0);
        t1 = fmaf(wr[k + 1], cr[k + 1], t1);
        t2 = fmaf(wr[k + 2], cr[k + 2], t2);
        t3 = fmaf(wr[k + 3], cr[k + 3], t3);
      }
      t0 = fmaf(wr[48], cr[48], t0);
      float ttv = (t0 + t1) + (t2 + t3);
      float r = fmaf(sc3[o], ttv, sh3[o]) + xp[o * HW];
      op[o * HW] = fmaxf(r, 0.f);
    }
  }
}

extern "C" void kernel_launch(void* const* d_in, const int* in_sizes, int n_in,
                              void* d_out, int out_size, void* d_ws, size_t ws_size,
                              hipStream_t stream) {
  const float* x   = (const float*)d_in[0];
  const float* w21 = (const float*)d_in[1];
  const float* w22 = (const float*)d_in[2];
  const float* g21 = (const float*)d_in[3];
  const float* b21 = (const float*)d_in[4];
  const float* g22 = (const float*)d_in[5];
  const float* b22 = (const float*)d_in[6];
  const float* g23 = (const float*)d_in[7];
  const float* b23 = (const float*)d_in[8];
  float* out = (float*)d_out;

  const size_t Y_F    = (size_t)NT * C_MID * HW;   // 3,211,264 floats
  const size_t CORR_F = (size_t)NT * KK * HW;      // 9,834,496
  const size_t TT_F   = (size_t)NT * C_IN * HW;    // 12,845,056
  const size_t ST_F   = 1024;

  float* ws   = (float*)d_ws;
  float2* y2  = (float2*)ws;                        // Y_F floats = Y_F/2 float2
  float* corr = ws + Y_F;
  float* st   = corr + CORR_F;
  float* tt   = st + ST_F;

  float* s1 = st;          float* q1 = s1 + 16;     // st[0..257] raw sums
  float* s2 = q1 + 16;     float* q2 = s2 + KK;
  float* s3 = q2 + KK;     float* q3 = s3 + 64;
  float* sc2 = st + 300;   float* sh2 = sc2 + KK;   // fallback-only
  float* sc3 = sh2 + KK;   float* sh3 = sc3 + 64;

  bool fast = ws_size >= (Y_F + CORR_F + ST_F + TT_F) * sizeof(float);

  hipMemsetAsync(st, 0, 258 * sizeof(float), stream);

  k1_conv  <<<784, 256, 0, stream>>>(x, w21, y2, s1);
  k3_corr  <<<512, 392, 0, stream>>>(y2, s1, g21, b21, corr);
  k3b_stats<<<NT * KK, 256, 0, stream>>>(corr, s2);

  if (fast) {
    k5_mat   <<<NPIX / 256, 256, 0, stream>>>(corr, s2, g22, b22, w22, tt);
    k5b_stats<<<NT * C_IN, 256, 0, stream>>>(tt, s3);
    k7_ew    <<<2048, 256, 0, stream>>>(tt, s3, g23, b23, x, out);
  } else {
    k_fin    <<<1, 64, 0, stream>>>(s2, q2, g22, b22, sc2, sh2, KK);
    k5_stats <<<512, 256, 0, stream>>>(corr, sc2, sh2, w22, s3, q3);
    k_fin    <<<1, 64, 0, stream>>>(s3, q3, g23, b23, sc3, sh3, C_IN);
    k7_out   <<<1024, 256, 0, stream>>>(corr, sc2, sh2, w22, sc3, sh3, x, out);
  }
}

// Round 9
// 293.476 us; speedup vs baseline: 1.3996x; 1.0020x over previous
//
#include <hip/hip_runtime.h>

#define HW 3136
#define W_ 56
#define C_IN 64
#define C_MID 16
#define KK 49
#define NT 64
#define NPIX (NT*HW)          // 200704
#define NF 200704.0f
#define EPS 1e-5f

// ---------------- K1: 1x1 conv 64->16, write y as channel-paired float2 ----------------
// No stats here (register pressure!). All 64 x-loads issued up front; (256,3) gives a
// 170-VGPR budget so xv[64]+acc[16] stay resident (round-3: VGPR=68 -> serialized loads,
// 109 us).
__global__ __launch_bounds__(256, 3) void k1_conv(const float* __restrict__ x,
                                                  const float* __restrict__ w21,
                                                  float2* __restrict__ y2) {
  int pix = blockIdx.x * 256 + threadIdx.x;   // grid = 784 covers NPIX exactly
  int n = pix / HW; int hw = pix - n * HW;
  const float* xp = x + (size_t)n * C_IN * HW + hw;

  float xv[C_IN];
#pragma unroll
  for (int j = 0; j < C_IN; ++j) xv[j] = xp[j * HW];

  float acc[C_MID];
#pragma unroll
  for (int o = 0; o < C_MID; ++o) acc[o] = 0.f;
#pragma unroll
  for (int o = 0; o < C_MID; ++o) {
    float a0 = 0.f, a1 = 0.f, a2 = 0.f, a3 = 0.f;
    const float* wr = w21 + o * C_IN;
#pragma unroll
    for (int j = 0; j < C_IN; j += 4) {
      a0 = fmaf(wr[j],     xv[j],     a0);
      a1 = fmaf(wr[j + 1], xv[j + 1], a1);
      a2 = fmaf(wr[j + 2], xv[j + 2], a2);
      a3 = fmaf(wr[j + 3], xv[j + 3], a3);
    }
    acc[o] = (a0 + a1) + (a2 + a3);
  }

  float2* yp = y2 + (size_t)n * 8 * HW + hw;
#pragma unroll
  for (int c2 = 0; c2 < 8; ++c2)
    yp[c2 * HW] = make_float2(acc[2 * c2], acc[2 * c2 + 1]);
}

// ---------------- K1b: BN1 stats from y (pure BW, per (n,c2) plane) ---------------------
__global__ __launch_bounds__(256) void k1b_stats(const float2* __restrict__ y2,
                                                 float* __restrict__ st /* s1[16] q1[16] */) {
  int c2 = blockIdx.x & 7;                 // grid = NT*8
  const float4* b4 = (const float4*)(y2 + (size_t)blockIdx.x * HW);
  float sA = 0.f, qA = 0.f, sB = 0.f, qB = 0.f;
  for (int i = threadIdx.x; i < HW / 2; i += 256) {   // 1568 float4 per plane
    float4 v = b4[i];                      // (p0.cA, p0.cB, p1.cA, p1.cB)
    sA += v.x + v.z; qA += v.x * v.x + v.z * v.z;
    sB += v.y + v.w; qB += v.y * v.y + v.w * v.w;
  }
#pragma unroll
  for (int off = 32; off > 0; off >>= 1) {
    sA += __shfl_xor(sA, off, 64); qA += __shfl_xor(qA, off, 64);
    sB += __shfl_xor(sB, off, 64); qB += __shfl_xor(qB, off, 64);
  }
  __shared__ float r[4][4];
  int wv = threadIdx.x >> 6; int lane = threadIdx.x & 63;
  if (lane == 0) { r[wv][0] = sA; r[wv][1] = qA; r[wv][2] = sB; r[wv][3] = qB; }
  __syncthreads();
  if (threadIdx.x == 0) {
    atomicAdd(&st[2 * c2],          r[0][0] + r[1][0] + r[2][0] + r[3][0]);
    atomicAdd(&st[16 + 2 * c2],     r[0][1] + r[1][1] + r[2][1] + r[3][1]);
    atomicAdd(&st[2 * c2 + 1],      r[0][2] + r[1][2] + r[2][2] + r[3][2]);
    atomicAdd(&st[16 + 2 * c2 + 1], r[0][3] + r[1][3] + r[2][3] + r[3][3]);
  }
}

// ---------------- k_fin (fallback path only) --------------------------------------------
__global__ void k_fin(const float* __restrict__ s, const float* __restrict__ q,
                      const float* __restrict__ g, const float* __restrict__ b,
                      float* __restrict__ sc, float* __restrict__ sh, int C) {
  int i = threadIdx.x;
  if (i < C) {
    float m = s[i] * (1.0f / NF);
    float v = q[i] * (1.0f / NF) - m * m;
    float inv = g[i] / sqrtf(v + EPS);
    sc[i] = inv;
    sh[i] = fmaf(-m, inv, b[i]);
  }
}

// ---------------- K3: 7x7x16 shifted correlation (float2 channels, fused BN1) -----------
#define TR 7
#define HR 13
#define HC 62
#define HSZ2 (HR*HC)          // 806 float2 per c2-plane
__global__ __launch_bounds__(392) void k3_corr(const float2* __restrict__ y2,
                                               const float* __restrict__ st /* s1,q1 */,
                                               const float* __restrict__ g21,
                                               const float* __restrict__ b21,
                                               float* __restrict__ corr) {
  __shared__ float2 Bl[8 * HSZ2];   // 51,584 B
  __shared__ float4 bn1[8];         // (scA, shA, scB, shB) per channel pair
  int tid = threadIdx.x;
  int n = blockIdx.x >> 3;
  int rt = blockIdx.x & 7;
  int r0 = rt * TR;
  int t = n & 7;
  int n2 = (n & ~7) | (t < 7 ? t + 1 : 7);   // time-shifted frame

  if (tid < 8) {
    int cA = 2 * tid, cB = 2 * tid + 1;
    float mA = st[cA] * (1.0f / NF), mB = st[cB] * (1.0f / NF);
    float vA = st[16 + cA] * (1.0f / NF) - mA * mA;
    float vB = st[16 + cB] * (1.0f / NF) - mB * mB;
    float iA = g21[cA] / sqrtf(vA + EPS);
    float iB = g21[cB] / sqrtf(vB + EPS);
    bn1[tid] = make_float4(iA, fmaf(-mA, iA, b21[cA]), iB, fmaf(-mB, iB, b21[cB]));
  }
  __syncthreads();

  // stage shifted-frame halo (post-BN1+relu; out-of-bounds = exact 0)
  const float2* yb = y2 + (size_t)n2 * 8 * HW;
  for (int idx = tid; idx < 8 * HSZ2; idx += 392) {
    int c2 = idx / HSZ2; int rem = idx - c2 * HSZ2;
    int rr = rem / HC; int cc = rem - rr * HC;
    int gr = r0 + rr - 3; int gc = cc - 3;
    float2 v = make_float2(0.f, 0.f);
    if (gr >= 0 && gr < 56 && gc >= 0 && gc < 56) {
      float2 raw = yb[c2 * HW + gr * W_ + gc];
      float4 p = bn1[c2];
      v.x = fmaxf(fmaf(p.x, raw.x, p.y), 0.f);
      v.y = fmaxf(fmaf(p.z, raw.y, p.w), 0.f);
    }
    Bl[idx] = v;
  }

  int ty = tid / W_; int tx = tid - ty * W_;   // ty in [0,7)
  int r = r0 + ty;
  float2 a2[8];
  const float2* ya = y2 + (size_t)n * 8 * HW + r * W_ + tx;
#pragma unroll
  for (int c2 = 0; c2 < 8; ++c2) {
    float2 raw = ya[c2 * HW];
    float4 p = bn1[c2];
    a2[c2] = make_float2(fmaxf(fmaf(p.x, raw.x, p.y), 0.f),
                         fmaxf(fmaf(p.z, raw.y, p.w), 0.f));
  }

  __syncthreads();

  float* cp = corr + (size_t)n * KK * HW + r * W_ + tx;
#pragma unroll
  for (int dy = 0; dy < 7; ++dy) {
#pragma unroll
    for (int dx = 0; dx < 7; ++dx) {
      const float2* bp = Bl + (ty + dy) * HC + (tx + dx);
      float v0 = 0.f, v1 = 0.f;
#pragma unroll
      for (int c2 = 0; c2 < 8; ++c2) {
        float2 bv = bp[c2 * HSZ2];
        v0 = fmaf(a2[c2].x, bv.x, v0);
        v1 = fmaf(a2[c2].y, bv.y, v1);
      }
      cp[(dy * 7 + dx) * HW] = (v0 + v1) * (1.0f / 16.0f);
    }
  }
}

// ---------------- K3b: per-(n,k) slice stats of corr ----------------
__global__ __launch_bounds__(256) void k3b_stats(const float* __restrict__ corr,
                                                 float* __restrict__ st /* s2[49] q2[49] */) {
  const float* base = corr + (size_t)blockIdx.x * HW;
  int k = blockIdx.x % KK;
  float s = 0.f, q = 0.f;
  const float4* b4 = (const float4*)base;
  for (int i = threadIdx.x; i < HW / 4; i += 256) {
    float4 v = b4[i];
    s += v.x + v.y + v.z + v.w;
    q += v.x * v.x + v.y * v.y + v.z * v.z + v.w * v.w;
  }
#pragma unroll
  for (int off = 32; off > 0; off >>= 1) {
    s += __shfl_xor(s, off, 64);
    q += __shfl_xor(q, off, 64);
  }
  __shared__ float rs[4], rq[4];
  int wv = threadIdx.x >> 6; int lane = threadIdx.x & 63;
  if (lane == 0) { rs[wv] = s; rq[wv] = q; }
  __syncthreads();
  if (threadIdx.x == 0) {
    atomicAdd(&st[k],      rs[0] + rs[1] + rs[2] + rs[3]);
    atomicAdd(&st[KK + k], rq[0] + rq[1] + rq[2] + rq[3]);
  }
}

// ---------------- K5_mat: 49->64 matvec, fused BN2, store pre-BN3 tt --------------------
__global__ __launch_bounds__(256, 3) void k5_mat(const float* __restrict__ corr,
                                                 const float* __restrict__ st /* s2,q2 */,
                                                 const float* __restrict__ g22,
                                                 const float* __restrict__ b22,
                                                 const float* __restrict__ w22,
                                                 float* __restrict__ tt) {
  __shared__ float bsc[KK], bsh[KK];
  if (threadIdx.x < KK) {
    int k = threadIdx.x;
    float m = st[k] * (1.0f / NF);
    float v = st[KK + k] * (1.0f / NF) - m * m;
    float inv = g22[k] / sqrtf(v + EPS);
    bsc[k] = inv;
    bsh[k] = fmaf(-m, inv, b22[k]);
  }
  __syncthreads();

  int pix = blockIdx.x * 256 + threadIdx.x;   // grid = 784 exactly covers NPIX
  int n = pix / HW; int hw = pix - n * HW;
  const float* cp = corr + (size_t)n * KK * HW + hw;
  float cr[KK];
#pragma unroll
  for (int k = 0; k < KK; ++k)
    cr[k] = fmaxf(fmaf(bsc[k], cp[k * HW], bsh[k]), 0.f);

  float* tp = tt + (size_t)n * C_IN * HW + hw;
#pragma unroll 4
  for (int o = 0; o < 64; ++o) {
    const float* wr = w22 + o * KK;
    float t0 = 0.f, t1 = 0.f, t2 = 0.f, t3 = 0.f;
#pragma unroll
    for (int k = 0; k < 48; k += 4) {
      t0 = fmaf(wr[k],     cr[k],     t0);
      t1 = fmaf(wr[k + 1], cr[k + 1], t1);
      t2 = fmaf(wr[k + 2], cr[k + 2], t2);
      t3 = fmaf(wr[k + 3], cr[k + 3], t3);
    }
    t0 = fmaf(wr[48], cr[48], t0);
    tp[o * HW] = (t0 + t1) + (t2 + t3);
  }
}

// ---------------- K5b: per-(n,o) plane stats of tt (pure BW) ----------------
__global__ __launch_bounds__(256) void k5b_stats(const float* __restrict__ tt,
                                                 float* __restrict__ st /* s3[64] q3[64] */) {
  const float4* b4 = (const float4*)(tt + (size_t)blockIdx.x * HW);
  int o = blockIdx.x & 63;
  float s = 0.f, q = 0.f;
  for (int i = threadIdx.x; i < HW / 4; i += 256) {
    float4 v = b4[i];
    s += v.x + v.y + v.z + v.w;
    q += v.x * v.x + v.y * v.y + v.z * v.z + v.w * v.w;
  }
#pragma unroll
  for (int off = 32; off > 0; off >>= 1) {
    s += __shfl_xor(s, off, 64);
    q += __shfl_xor(q, off, 64);
  }
  __shared__ float rs[4], rq[4];
  int wv = threadIdx.x >> 6; int lane = threadIdx.x & 63;
  if (lane == 0) { rs[wv] = s; rq[wv] = q; }
  __syncthreads();
  if (threadIdx.x == 0) {
    atomicAdd(&st[o],      rs[0] + rs[1] + rs[2] + rs[3]);
    atomicAdd(&st[64 + o], rq[0] + rq[1] + rq[2] + rq[3]);
  }
}

// ---------------- K7_ew: fused BN3 + residual + relu ----------------
__global__ __launch_bounds__(256) void k7_ew(const float* __restrict__ tt,
                                             const float* __restrict__ st /* s3,q3 */,
                                             const float* __restrict__ g23,
                                             const float* __restrict__ b23,
                                             const float* __restrict__ x,
                                             float* __restrict__ out) {
  __shared__ float csc[64], csh[64];
  if (threadIdx.x < 64) {
    int o = threadIdx.x;
    float m = st[o] * (1.0f / NF);
    float v = st[64 + o] * (1.0f / NF) - m * m;
    float inv = g23[o] / sqrtf(v + EPS);
    csc[o] = inv;
    csh[o] = fmaf(-m, inv, b23[o]);
  }
  __syncthreads();

  const int tot4 = NPIX * C_IN / 4;   // 3,211,264
  const float4* t4 = (const float4*)tt;
  const float4* x4 = (const float4*)x;
  float4* o4 = (float4*)out;
  for (int i = blockIdx.x * 256 + threadIdx.x; i < tot4; i += gridDim.x * 256) {
    int plane = i / (HW / 4);
    int o = plane & 63;
    float a = csc[o], b = csh[o];
    float4 t = t4[i];
    float4 xv = x4[i];
    float4 r;
    r.x = fmaxf(fmaf(a, t.x, b) + xv.x, 0.f);
    r.y = fmaxf(fmaf(a, t.y, b) + xv.y, 0.f);
    r.z = fmaxf(fmaf(a, t.z, b) + xv.z, 0.f);
    r.w = fmaxf(fmaf(a, t.w, b) + xv.w, 0.f);
    o4[i] = r;
  }
}

// ---------------- Fallback K5: matvec + BN3 stats only (small-ws path) ------------------
__global__ __launch_bounds__(256, 3) void k5_stats(const float* __restrict__ corr,
                                                   const float* __restrict__ sc2,
                                                   const float* __restrict__ sh2,
                                                   const float* __restrict__ w22,
                                                   float* __restrict__ s3, float* __restrict__ q3) {
  __shared__ float aS[64], aQ[64];
  if (threadIdx.x < 64) { aS[threadIdx.x] = 0.f; aQ[threadIdx.x] = 0.f; }
  __syncthreads();
  int lane = threadIdx.x & 63;
  for (int pix = blockIdx.x * 256 + threadIdx.x; pix < NPIX; pix += gridDim.x * 256) {
    int n = pix / HW; int hw = pix - n * HW;
    const float* cp = corr + (size_t)n * KK * HW + hw;
    float cr[KK];
#pragma unroll
    for (int k = 0; k < KK; ++k)
      cr[k] = fmaxf(fmaf(sc2[k], cp[k * HW], sh2[k]), 0.f);
    for (int o = 0; o < 64; ++o) {
      const float* wr = w22 + o * KK;
      float t0 = 0.f, t1 = 0.f, t2 = 0.f, t3 = 0.f;
#pragma unroll
      for (int k = 0; k < 48; k += 4) {
        t0 = fmaf(wr[k],     cr[k],     t0);
        t1 = fmaf(wr[k + 1], cr[k + 1], t1);
        t2 = fmaf(wr[k + 2], cr[k + 2], t2);
        t3 = fmaf(wr[k + 3], cr[k + 3], t3);
      }
      t0 = fmaf(wr[48], cr[48], t0);
      float ttv = (t0 + t1) + (t2 + t3);
      float vs = ttv, vq = ttv * ttv;
#pragma unroll
      for (int off = 32; off > 0; off >>= 1) {
        vs += __shfl_xor(vs, off, 64);
        vq += __shfl_xor(vq, off, 64);
      }
      if (lane == 0) { atomicAdd(&aS[o], vs); atomicAdd(&aQ[o], vq); }
    }
  }
  __syncthreads();
  if (threadIdx.x < 64) {
    atomicAdd(&s3[threadIdx.x], aS[threadIdx.x]);
    atomicAdd(&q3[threadIdx.x], aQ[threadIdx.x]);
  }
}

// ---------------- Fallback K7: recompute matvec + BN3 + residual + relu -----------------
__global__ __launch_bounds__(256, 3) void k7_out(const float* __restrict__ corr,
                                                 const float* __restrict__ sc2,
                                                 const float* __restrict__ sh2,
                                                 const float* __restrict__ w22,
                                                 const float* __restrict__ sc3,
                                                 const float* __restrict__ sh3,
                                                 const float* __restrict__ x,
                                                 float* __restrict__ out) {
  for (int pix = blockIdx.x * 256 + threadIdx.x; pix < NPIX; pix += gridDim.x * 256) {
    int n = pix / HW; int hw = pix - n * HW;
    const float* cp = corr + (size_t)n * KK * HW + hw;
    float cr[KK];
#pragma unroll
    for (int k = 0; k < KK; ++k)
      cr[k] = fmaxf(fmaf(sc2[k], cp[k * HW], sh2[k]), 0.f);
    const float* xp = x + (size_t)n * C_IN * HW + hw;
    float* op = out + (size_t)n * C_IN * HW + hw;
#pragma unroll 4
    for (int o = 0; o < 64; ++o) {
      const float* wr = w22 + o * KK;
      float t0 = 0.f, t1 = 0.f, t2 = 0.f, t3 = 0.f;
#pragma unroll
      for (int k = 0; k < 48; k += 4) {
        t0 = fmaf(wr[k],     cr[k],     t0);
        t1 = fmaf(wr[k + 1], cr[k + 1], t1);
        t2 = fmaf(wr[k + 2], cr[k + 2], t2);
        t3 = fmaf(wr[k + 3], cr[k + 3], t3);
      }
      t0 = fmaf(wr[48], cr[48], t0);
      float ttv = (t0 + t1) + (t2 + t3);
      float r = fmaf(sc3[o], ttv, sh3[o]) + xp[o * HW];
      op[o * HW] = fmaxf(r, 0.f);
    }
  }
}

extern "C" void kernel_launch(void* const* d_in, const int* in_sizes, int n_in,
                              void* d_out, int out_size, void* d_ws, size_t ws_size,
                              hipStream_t stream) {
  const float* x   = (const float*)d_in[0];
  const float* w21 = (const float*)d_in[1];
  const float* w22 = (const float*)d_in[2];
  const float* g21 = (const float*)d_in[3];
  const float* b21 = (const float*)d_in[4];
  const float* g22 = (const float*)d_in[5];
  const float* b22 = (const float*)d_in[6];
  const float* g23 = (const float*)d_in[7];
  const float* b23 = (const float*)d_in[8];
  float* out = (float*)d_out;

  const size_t Y_F    = (size_t)NT * C_MID * HW;   // 3,211,264 floats
  const size_t CORR_F = (size_t)NT * KK * HW;      // 9,834,496
  const size_t TT_F   = (size_t)NT * C_IN * HW;    // 12,845,056
  const size_t ST_F   = 1024;

  float* ws   = (float*)d_ws;
  float2* y2  = (float2*)ws;                        // Y_F floats = Y_F/2 float2
  float* corr = ws + Y_F;
  float* st   = corr + CORR_F;
  float* tt   = st + ST_F;

  float* s1 = st;          float* q1 = s1 + 16;     // st[0..257] raw sums
  float* s2 = q1 + 16;     float* q2 = s2 + KK;
  float* s3 = q2 + KK;     float* q3 = s3 + 64;
  float* sc2 = st + 300;   float* sh2 = sc2 + KK;   // fallback-only
  float* sc3 = sh2 + KK;   float* sh3 = sc3 + 64;

  bool fast = ws_size >= (Y_F + CORR_F + ST_F + TT_F) * sizeof(float);

  hipMemsetAsync(st, 0, 258 * sizeof(float), stream);

  k1_conv  <<<784, 256, 0, stream>>>(x, w21, y2);
  k1b_stats<<<NT * 8, 256, 0, stream>>>(y2, s1);
  k3_corr  <<<512, 392, 0, stream>>>(y2, s1, g21, b21, corr);
  k3b_stats<<<NT * KK, 256, 0, stream>>>(corr, s2);

  if (fast) {
    k5_mat   <<<NPIX / 256, 256, 0, stream>>>(corr, s2, g22, b22, w22, tt);
    k5b_stats<<<NT * C_IN, 256, 0, stream>>>(tt, s3);
    k7_ew    <<<2048, 256, 0, stream>>>(tt, s3, g23, b23, x, out);
  } else {
    k_fin    <<<1, 64, 0, stream>>>(s2, q2, g22, b22, sc2, sh2, KK);
    k5_stats <<<512, 256, 0, stream>>>(corr, sc2, sh2, w22, s3, q3);
    k_fin    <<<1, 64, 0, stream>>>(s3, q3, g23, b23, sc3, sh3, C_IN);
    k7_out   <<<1024, 256, 0, stream>>>(corr, sc2, sh2, w22, sc3, sh3, x, out);
  }
}

// Round 14
// 276.112 us; speedup vs baseline: 1.4876x; 1.0629x over previous
//
#include <hip/hip_runtime.h>

#define HW 3136
#define W_ 56
#define C_IN 64
#define C_MID 16
#define KK 49
#define NT 64
#define NPIX (NT*HW)          // 200704
#define NF 200704.0f
#define EPS 1e-5f

// ---------------- K0: transpose weights so inner loops read wave-uniform [*][o] ---------
__global__ __launch_bounds__(256) void k0_tw(const float* __restrict__ w21,
                                             const float* __restrict__ w22,
                                             float* __restrict__ w21t,
                                             float* __restrict__ w22t) {
  int i = blockIdx.x * 256 + threadIdx.x;
  if (i < C_MID * C_IN) { int o = i / C_IN; int j = i - o * C_IN; w21t[j * C_MID + o] = w21[i]; }
  if (i < C_IN * KK)    { int o = i / KK;   int k = i - o * KK;   w22t[k * C_IN + o] = w22[i]; }
}

// ---------------- K1: 1x1 conv 64->16, OUTER-PRODUCT form -------------------------------
// acc[16] are accumulators (cannot be rematerialized -> stay in VGPRs); x streamed one
// value at a time; w21t[j][o] is wave-uniform -> s_load. Round-9 evidence: input-resident
// forms (xv[64] live) get remat'd by the allocator at ~56-68 VGPR regardless of
// launch_bounds -> 107 us. Accumulator-resident live set is ~30 VGPR.
__global__ __launch_bounds__(256) void k1_conv(const float* __restrict__ x,
                                               const float* __restrict__ w21t,
                                               float2* __restrict__ y2) {
  int pix = blockIdx.x * 256 + threadIdx.x;   // grid = 784 covers NPIX exactly
  int n = pix / HW; int hw = pix - n * HW;
  const float* xp = x + (size_t)n * C_IN * HW + hw;

  float acc[C_MID];
#pragma unroll
  for (int o = 0; o < C_MID; ++o) acc[o] = 0.f;

#pragma unroll
  for (int j = 0; j < C_IN; ++j) {
    float xj = xp[j * HW];
    const float* wt = w21t + j * C_MID;
#pragma unroll
    for (int o = 0; o < C_MID; ++o)
      acc[o] = fmaf(wt[o], xj, acc[o]);
  }

  float2* yp = y2 + (size_t)n * 8 * HW + hw;
#pragma unroll
  for (int c2 = 0; c2 < 8; ++c2)
    yp[c2 * HW] = make_float2(acc[2 * c2], acc[2 * c2 + 1]);
}

// ---------------- K1b: BN1 stats from y (pure BW, per (n,c2) plane) ---------------------
__global__ __launch_bounds__(256) void k1b_stats(const float2* __restrict__ y2,
                                                 float* __restrict__ st /* s1[16] q1[16] */) {
  int c2 = blockIdx.x & 7;                 // grid = NT*8
  const float4* b4 = (const float4*)(y2 + (size_t)blockIdx.x * HW);
  float sA = 0.f, qA = 0.f, sB = 0.f, qB = 0.f;
  for (int i = threadIdx.x; i < HW / 2; i += 256) {   // 1568 float4 per plane
    float4 v = b4[i];                      // (p0.cA, p0.cB, p1.cA, p1.cB)
    sA += v.x + v.z; qA += v.x * v.x + v.z * v.z;
    sB += v.y + v.w; qB += v.y * v.y + v.w * v.w;
  }
#pragma unroll
  for (int off = 32; off > 0; off >>= 1) {
    sA += __shfl_xor(sA, off, 64); qA += __shfl_xor(qA, off, 64);
    sB += __shfl_xor(sB, off, 64); qB += __shfl_xor(qB, off, 64);
  }
  __shared__ float r[4][4];
  int wv = threadIdx.x >> 6; int lane = threadIdx.x & 63;
  if (lane == 0) { r[wv][0] = sA; r[wv][1] = qA; r[wv][2] = sB; r[wv][3] = qB; }
  __syncthreads();
  if (threadIdx.x == 0) {
    atomicAdd(&st[2 * c2],          r[0][0] + r[1][0] + r[2][0] + r[3][0]);
    atomicAdd(&st[16 + 2 * c2],     r[0][1] + r[1][1] + r[2][1] + r[3][1]);
    atomicAdd(&st[2 * c2 + 1],      r[0][2] + r[1][2] + r[2][2] + r[3][2]);
    atomicAdd(&st[16 + 2 * c2 + 1], r[0][3] + r[1][3] + r[2][3] + r[3][3]);
  }
}

// ---------------- k_fin (fallback path only) --------------------------------------------
__global__ void k_fin(const float* __restrict__ s, const float* __restrict__ q,
                      const float* __restrict__ g, const float* __restrict__ b,
                      float* __restrict__ sc, float* __restrict__ sh, int C) {
  int i = threadIdx.x;
  if (i < C) {
    float m = s[i] * (1.0f / NF);
    float v = q[i] * (1.0f / NF) - m * m;
    float inv = g[i] / sqrtf(v + EPS);
    sc[i] = inv;
    sh[i] = fmaf(-m, inv, b[i]);
  }
}

// ---------------- K3: 7x7x16 shifted correlation (float2 channels, fused BN1) -----------
#define TR 7
#define HR 13
#define HC 62
#define HSZ2 (HR*HC)          // 806 float2 per c2-plane
__global__ __launch_bounds__(392) void k3_corr(const float2* __restrict__ y2,
                                               const float* __restrict__ st /* s1,q1 */,
                                               const float* __restrict__ g21,
                                               const float* __restrict__ b21,
                                               float* __restrict__ corr) {
  __shared__ float2 Bl[8 * HSZ2];   // 51,584 B
  __shared__ float4 bn1[8];         // (scA, shA, scB, shB) per channel pair
  int tid = threadIdx.x;
  int n = blockIdx.x >> 3;
  int rt = blockIdx.x & 7;
  int r0 = rt * TR;
  int t = n & 7;
  int n2 = (n & ~7) | (t < 7 ? t + 1 : 7);   // time-shifted frame

  if (tid < 8) {
    int cA = 2 * tid, cB = 2 * tid + 1;
    float mA = st[cA] * (1.0f / NF), mB = st[cB] * (1.0f / NF);
    float vA = st[16 + cA] * (1.0f / NF) - mA * mA;
    float vB = st[16 + cB] * (1.0f / NF) - mB * mB;
    float iA = g21[cA] / sqrtf(vA + EPS);
    float iB = g21[cB] / sqrtf(vB + EPS);
    bn1[tid] = make_float4(iA, fmaf(-mA, iA, b21[cA]), iB, fmaf(-mB, iB, b21[cB]));
  }
  __syncthreads();

  // stage shifted-frame halo (post-BN1+relu; out-of-bounds = exact 0)
  const float2* yb = y2 + (size_t)n2 * 8 * HW;
  for (int idx = tid; idx < 8 * HSZ2; idx += 392) {
    int c2 = idx / HSZ2; int rem = idx - c2 * HSZ2;
    int rr = rem / HC; int cc = rem - rr * HC;
    int gr = r0 + rr - 3; int gc = cc - 3;
    float2 v = make_float2(0.f, 0.f);
    if (gr >= 0 && gr < 56 && gc >= 0 && gc < 56) {
      float2 raw = yb[c2 * HW + gr * W_ + gc];
      float4 p = bn1[c2];
      v.x = fmaxf(fmaf(p.x, raw.x, p.y), 0.f);
      v.y = fmaxf(fmaf(p.z, raw.y, p.w), 0.f);
    }
    Bl[idx] = v;
  }

  int ty = tid / W_; int tx = tid - ty * W_;   // ty in [0,7)
  int r = r0 + ty;
  float2 a2[8];
  const float2* ya = y2 + (size_t)n * 8 * HW + r * W_ + tx;
#pragma unroll
  for (int c2 = 0; c2 < 8; ++c2) {
    float2 raw = ya[c2 * HW];
    float4 p = bn1[c2];
    a2[c2] = make_float2(fmaxf(fmaf(p.x, raw.x, p.y), 0.f),
                         fmaxf(fmaf(p.z, raw.y, p.w), 0.f));
  }

  __syncthreads();

  float* cp = corr + (size_t)n * KK * HW + r * W_ + tx;
#pragma unroll
  for (int dy = 0; dy < 7; ++dy) {
#pragma unroll
    for (int dx = 0; dx < 7; ++dx) {
      const float2* bp = Bl + (ty + dy) * HC + (tx + dx);
      float v0 = 0.f, v1 = 0.f;
#pragma unroll
      for (int c2 = 0; c2 < 8; ++c2) {
        float2 bv = bp[c2 * HSZ2];
        v0 = fmaf(a2[c2].x, bv.x, v0);
        v1 = fmaf(a2[c2].y, bv.y, v1);
      }
      cp[(dy * 7 + dx) * HW] = (v0 + v1) * (1.0f / 16.0f);
    }
  }
}

// ---------------- K3b: per-(n,k) slice stats of corr ----------------
__global__ __launch_bounds__(256) void k3b_stats(const float* __restrict__ corr,
                                                 float* __restrict__ st /* s2[49] q2[49] */) {
  const float* base = corr + (size_t)blockIdx.x * HW;
  int k = blockIdx.x % KK;
  float s = 0.f, q = 0.f;
  const float4* b4 = (const float4*)base;
  for (int i = threadIdx.x; i < HW / 4; i += 256) {
    float4 v = b4[i];
    s += v.x + v.y + v.z + v.w;
    q += v.x * v.x + v.y * v.y + v.z * v.z + v.w * v.w;
  }
#pragma unroll
  for (int off = 32; off > 0; off >>= 1) {
    s += __shfl_xor(s, off, 64);
    q += __shfl_xor(q, off, 64);
  }
  __shared__ float rs[4], rq[4];
  int wv = threadIdx.x >> 6; int lane = threadIdx.x & 63;
  if (lane == 0) { rs[wv] = s; rq[wv] = q; }
  __syncthreads();
  if (threadIdx.x == 0) {
    atomicAdd(&st[k],      rs[0] + rs[1] + rs[2] + rs[3]);
    atomicAdd(&st[KK + k], rq[0] + rq[1] + rq[2] + rq[3]);
  }
}

// ---------------- K5_mat: 49->64 matvec, OUTER-PRODUCT form, fused BN2 ------------------
// acc[64] accumulator-resident (non-remat-able); corr streamed one coalesced load per k;
// w22t[k][o] wave-uniform -> s_load. Round-9: the dot-product form was allocator-remat'd
// at VGPR=56 (launch_bounds(256,3) had NO effect) -> 53 us of latency stalls.
__global__ __launch_bounds__(256) void k5_mat(const float* __restrict__ corr,
                                              const float* __restrict__ st /* s2,q2 */,
                                              const float* __restrict__ g22,
                                              const float* __restrict__ b22,
                                              const float* __restrict__ w22t,
                                              float* __restrict__ tt) {
  __shared__ float bsc[KK], bsh[KK];
  if (threadIdx.x < KK) {
    int k = threadIdx.x;
    float m = st[k] * (1.0f / NF);
    float v = st[KK + k] * (1.0f / NF) - m * m;
    float inv = g22[k] / sqrtf(v + EPS);
    bsc[k] = inv;
    bsh[k] = fmaf(-m, inv, b22[k]);
  }
  __syncthreads();

  int pix = blockIdx.x * 256 + threadIdx.x;   // grid = 784 exactly covers NPIX
  int n = pix / HW; int hw = pix - n * HW;
  const float* cp = corr + (size_t)n * KK * HW + hw;

  float acc[C_IN];
#pragma unroll
  for (int o = 0; o < C_IN; ++o) acc[o] = 0.f;

#pragma unroll
  for (int k = 0; k < KK; ++k) {
    float c = fmaxf(fmaf(bsc[k], cp[k * HW], bsh[k]), 0.f);
    const float* wt = w22t + k * C_IN;
#pragma unroll
    for (int o = 0; o < C_IN; ++o)
      acc[o] = fmaf(wt[o], c, acc[o]);
  }

  float* tp = tt + (size_t)n * C_IN * HW + hw;
#pragma unroll
  for (int o = 0; o < C_IN; ++o)
    tp[o * HW] = acc[o];
}

// ---------------- K5b: per-(n,o) plane stats of tt (pure BW) ----------------
__global__ __launch_bounds__(256) void k5b_stats(const float* __restrict__ tt,
                                                 float* __restrict__ st /* s3[64] q3[64] */) {
  const float4* b4 = (const float4*)(tt + (size_t)blockIdx.x * HW);
  int o = blockIdx.x & 63;
  float s = 0.f, q = 0.f;
  for (int i = threadIdx.x; i < HW / 4; i += 256) {
    float4 v = b4[i];
    s += v.x + v.y + v.z + v.w;
    q += v.x * v.x + v.y * v.y + v.z * v.z + v.w * v.w;
  }
#pragma unroll
  for (int off = 32; off > 0; off >>= 1) {
    s += __shfl_xor(s, off, 64);
    q += __shfl_xor(q, off, 64);
  }
  __shared__ float rs[4], rq[4];
  int wv = threadIdx.x >> 6; int lane = threadIdx.x & 63;
  if (lane == 0) { rs[wv] = s; rq[wv] = q; }
  __syncthreads();
  if (threadIdx.x == 0) {
    atomicAdd(&st[o],      rs[0] + rs[1] + rs[2] + rs[3]);
    atomicAdd(&st[64 + o], rq[0] + rq[1] + rq[2] + rq[3]);
  }
}

// ---------------- K7_ew: fused BN3 + residual + relu ----------------
__global__ __launch_bounds__(256) void k7_ew(const float* __restrict__ tt,
                                             const float* __restrict__ st /* s3,q3 */,
                                             const float* __restrict__ g23,
                                             const float* __restrict__ b23,
                                             const float* __restrict__ x,
                                             float* __restrict__ out) {
  __shared__ float csc[64], csh[64];
  if (threadIdx.x < 64) {
    int o = threadIdx.x;
    float m = st[o] * (1.0f / NF);
    float v = st[64 + o] * (1.0f / NF) - m * m;
    float inv = g23[o] / sqrtf(v + EPS);
    csc[o] = inv;
    csh[o] = fmaf(-m, inv, b23[o]);
  }
  __syncthreads();

  const int tot4 = NPIX * C_IN / 4;   // 3,211,264
  const float4* t4 = (const float4*)tt;
  const float4* x4 = (const float4*)x;
  float4* o4 = (float4*)out;
  for (int i = blockIdx.x * 256 + threadIdx.x; i < tot4; i += gridDim.x * 256) {
    int plane = i / (HW / 4);
    int o = plane & 63;
    float a = csc[o], b = csh[o];
    float4 t = t4[i];
    float4 xv = x4[i];
    float4 r;
    r.x = fmaxf(fmaf(a, t.x, b) + xv.x, 0.f);
    r.y = fmaxf(fmaf(a, t.y, b) + xv.y, 0.f);
    r.z = fmaxf(fmaf(a, t.z, b) + xv.z, 0.f);
    r.w = fmaxf(fmaf(a, t.w, b) + xv.w, 0.f);
    o4[i] = r;
  }
}

// ---------------- Fallback K5: matvec + BN3 stats only (small-ws path) ------------------
__global__ __launch_bounds__(256) void k5_stats(const float* __restrict__ corr,
                                                const float* __restrict__ sc2,
                                                const float* __restrict__ sh2,
                                                const float* __restrict__ w22,
                                                float* __restrict__ s3, float* __restrict__ q3) {
  __shared__ float aS[64], aQ[64];
  if (threadIdx.x < 64) { aS[threadIdx.x] = 0.f; aQ[threadIdx.x] = 0.f; }
  __syncthreads();
  int lane = threadIdx.x & 63;
  for (int pix = blockIdx.x * 256 + threadIdx.x; pix < NPIX; pix += gridDim.x * 256) {
    int n = pix / HW; int hw = pix - n * HW;
    const float* cp = corr + (size_t)n * KK * HW + hw;
    float cr[KK];
#pragma unroll
    for (int k = 0; k < KK; ++k)
      cr[k] = fmaxf(fmaf(sc2[k], cp[k * HW], sh2[k]), 0.f);
    for (int o = 0; o < 64; ++o) {
      const float* wr = w22 + o * KK;
      float t0 = 0.f, t1 = 0.f, t2 = 0.f, t3 = 0.f;
#pragma unroll
      for (int k = 0; k < 48; k += 4) {
        t0 = fmaf(wr[k],     cr[k],     t0);
        t1 = fmaf(wr[k + 1], cr[k + 1], t1);
        t2 = fmaf(wr[k + 2], cr[k + 2], t2);
        t3 = fmaf(wr[k + 3], cr[k + 3], t3);
      }
      t0 = fmaf(wr[48], cr[48], t0);
      float ttv = (t0 + t1) + (t2 + t3);
      float vs = ttv, vq = ttv * ttv;
#pragma unroll
      for (int off = 32; off > 0; off >>= 1) {
        vs += __shfl_xor(vs, off, 64);
        vq += __shfl_xor(vq, off, 64);
      }
      if (lane == 0) { atomicAdd(&aS[o], vs); atomicAdd(&aQ[o], vq); }
    }
  }
  __syncthreads();
  if (threadIdx.x < 64) {
    atomicAdd(&s3[threadIdx.x], aS[threadIdx.x]);
    atomicAdd(&q3[threadIdx.x], aQ[threadIdx.x]);
  }
}

// ---------------- Fallback K7: recompute matvec + BN3 + residual + relu -----------------
__global__ __launch_bounds__(256) void k7_out(const float* __restrict__ corr,
                                              const float* __restrict__ sc2,
                                              const float* __restrict__ sh2,
                                              const float* __restrict__ w22,
                                              const float* __restrict__ sc3,
                                              const float* __restrict__ sh3,
                                              const float* __restrict__ x,
                                              float* __restrict__ out) {
  for (int pix = blockIdx.x * 256 + threadIdx.x; pix < NPIX; pix += gridDim.x * 256) {
    int n = pix / HW; int hw = pix - n * HW;
    const float* cp = corr + (size_t)n * KK * HW + hw;
    float cr[KK];
#pragma unroll
    for (int k = 0; k < KK; ++k)
      cr[k] = fmaxf(fmaf(sc2[k], cp[k * HW], sh2[k]), 0.f);
    const float* xp = x + (size_t)n * C_IN * HW + hw;
    float* op = out + (size_t)n * C_IN * HW + hw;
#pragma unroll 4
    for (int o = 0; o < 64; ++o) {
      const float* wr = w22 + o * KK;
      float t0 = 0.f, t1 = 0.f, t2 = 0.f, t3 = 0.f;
#pragma unroll
      for (int k = 0; k < 48; k += 4) {
        t0 = fmaf(wr[k],     cr[k],     t0);
        t1 = fmaf(wr[k + 1], cr[k + 1], t1);
        t2 = fmaf(wr[k + 2], cr[k + 2], t2);
        t3 = fmaf(wr[k + 3], cr[k + 3], t3);
      }
      t0 = fmaf(wr[48], cr[48], t0);
      float ttv = (t0 + t1) + (t2 + t3);
      float r = fmaf(sc3[o], ttv, sh3[o]) + xp[o * HW];
      op[o * HW] = fmaxf(r, 0.f);
    }
  }
}

extern "C" void kernel_launch(void* const* d_in, const int* in_sizes, int n_in,
                              void* d_out, int out_size, void* d_ws, size_t ws_size,
                              hipStream_t stream) {
  const float* x   = (const float*)d_in[0];
  const float* w21 = (const float*)d_in[1];
  const float* w22 = (const float*)d_in[2];
  const float* g21 = (const float*)d_in[3];
  const float* b21 = (const float*)d_in[4];
  const float* g22 = (const float*)d_in[5];
  const float* b22 = (const float*)d_in[6];
  const float* g23 = (const float*)d_in[7];
  const float* b23 = (const float*)d_in[8];
  float* out = (float*)d_out;

  const size_t Y_F    = (size_t)NT * C_MID * HW;   // 3,211,264 floats
  const size_t CORR_F = (size_t)NT * KK * HW;      // 9,834,496
  const size_t TT_F   = (size_t)NT * C_IN * HW;    // 12,845,056
  const size_t ST_F   = 1024;
  const size_t W21T_F = (size_t)C_MID * C_IN;      // 1,024
  const size_t W22T_F = (size_t)KK * C_IN;         // 3,136

  float* ws   = (float*)d_ws;
  float2* y2  = (float2*)ws;                        // Y_F floats = Y_F/2 float2
  float* corr = ws + Y_F;
  float* st   = corr + CORR_F;
  float* w21t = st + ST_F;
  float* w22t = w21t + W21T_F;
  float* tt   = w22t + W22T_F;

  float* s1 = st;          float* q1 = s1 + 16;     // st[0..257] raw sums
  float* s2 = q1 + 16;     float* q2 = s2 + KK;
  float* s3 = q2 + KK;     float* q3 = s3 + 64;
  float* sc2 = st + 300;   float* sh2 = sc2 + KK;   // fallback-only
  float* sc3 = sh2 + KK;   float* sh3 = sc3 + 64;

  bool fast = ws_size >= (Y_F + CORR_F + ST_F + W21T_F + W22T_F + TT_F) * sizeof(float);

  hipMemsetAsync(st, 0, 258 * sizeof(float), stream);

  k0_tw    <<<13, 256, 0, stream>>>(w21, w22, w21t, w22t);
  k1_conv  <<<784, 256, 0, stream>>>(x, w21t, y2);
  k1b_stats<<<NT * 8, 256, 0, stream>>>(y2, s1);
  k3_corr  <<<512, 392, 0, stream>>>(y2, s1, g21, b21, corr);
  k3b_stats<<<NT * KK, 256, 0, stream>>>(corr, s2);

  if (fast) {
    k5_mat   <<<NPIX / 256, 256, 0, stream>>>(corr, s2, g22, b22, w22t, tt);
    k5b_stats<<<NT * C_IN, 256, 0, stream>>>(tt, s3);
    k7_ew    <<<2048, 256, 0, stream>>>(tt, s3, g23, b23, x, out);
  } else {
    k_fin    <<<1, 64, 0, stream>>>(s2, q2, g22, b22, sc2, sh2, KK);
    k5_stats <<<512, 256, 0, stream>>>(corr, sc2, sh2, w22, s3, q3);
    k_fin    <<<1, 64, 0, stream>>>(s3, q3, g23, b23, sc3, sh3, C_IN);
    k7_out   <<<1024, 256, 0, stream>>>(corr, sc2, sh2, w22, sc3, sh3, x, out);
  }
}